// Round 1
// baseline (564.311 us; speedup 1.0000x reference)
//
#include <hip/hip_runtime.h>
#include <math.h>

#define N_NODES 50000
#define DEG     16
#define BATCH   1024
#define F_IN    128
#define HID     128
#define F_OUT   64
#define FE_H    8
#define FN_H    128
#define GP_H    128
#define E_TOT   (N_NODES * DEG)

// ---------------------------------------------------------------------------
// 1. init: deg = 1.0 (self-loop term), nsf = 0, feat accumulator = 0
// ---------------------------------------------------------------------------
__global__ void k_init(float* __restrict__ deg, float* __restrict__ nsf,
                       float* __restrict__ feat) {
    int i = blockIdx.x * blockDim.x + threadIdx.x;
    if (i < N_NODES) { deg[i] = 1.0f; nsf[i] = 0.0f; }
    if (i < F_OUT) feat[i] = 0.0f;
}

// ---------------------------------------------------------------------------
// 2. per-edge: deg scatter (+1 per appearance as neighbor) and
//    nsf scatter of fe-MLP(A_w)  (FE_H=8 hidden units)
// ---------------------------------------------------------------------------
__global__ void k_edge(const int* __restrict__ nbr, const float* __restrict__ A_w,
                       const float* __restrict__ fe_w1, const float* __restrict__ fe_b1,
                       const float* __restrict__ fe_w2, const float* __restrict__ fe_b2,
                       float* __restrict__ deg, float* __restrict__ nsf) {
    int e = blockIdx.x * blockDim.x + threadIdx.x;
    if (e >= E_TOT) return;
    int   c = nbr[e];
    float v = A_w[e];
    float acc = fe_b2[0];
#pragma unroll
    for (int j = 0; j < FE_H; ++j) {
        float hj = fmaf(v, fe_w1[j], fe_b1[j]);
        acc = fmaf(fmaxf(hj, 0.0f), fe_w2[j], acc);
    }
    atomicAdd(&deg[c], 1.0f);
    atomicAdd(&nsf[c], acc);
}

// ---------------------------------------------------------------------------
// 3. matmul t[N,COLS] = h[N,128] @ W[128,COLS]   (f32, W staged in LDS)
// ---------------------------------------------------------------------------
template <int COLS>
__global__ __launch_bounds__(256) void k_matmul(const float* __restrict__ h,
                                                const float* __restrict__ W,
                                                float* __restrict__ t, int n) {
    constexpr int RP = 256 / COLS;  // rows per iteration
    __shared__ float Wl[128 * COLS];
    __shared__ float hs[RP][128];
    int tid = threadIdx.x;
    for (int idx = tid; idx < 128 * COLS; idx += 256) Wl[idx] = W[idx];
    int c  = tid % COLS;
    int rh = tid / COLS;
    for (int r0 = blockIdx.x * RP; r0 < n; r0 += gridDim.x * RP) {
        __syncthreads();  // Wl ready (iter 0) / previous compute done
        for (int idx = tid; idx < RP * 128; idx += 256) {
            int rr = r0 + idx / 128;
            hs[idx / 128][idx % 128] = (rr < n) ? h[rr * 128 + (idx % 128)] : 0.0f;
        }
        __syncthreads();
        int r = r0 + rh;
        if (r < n) {
            float acc = 0.0f;
#pragma unroll
            for (int k = 0; k < 128; ++k)
                acc = fmaf(hs[rh][k], Wl[k * COLS + c], acc);
            t[r * COLS + c] = acc;
        }
    }
}

// ---------------------------------------------------------------------------
// 4. aggregate: out[i,c] = sum_k rsqrt(d_i d_{nbr})*t[nbr,c] + t[i,c]/d_i + b[c]
//    one block per node, one thread per column
// ---------------------------------------------------------------------------
template <int COLS, bool RELU>
__global__ void k_agg(const float* __restrict__ t, const int* __restrict__ nbr,
                      const float* __restrict__ deg, const float* __restrict__ bias,
                      float* __restrict__ out) {
    int i = blockIdx.x;
    int c = threadIdx.x;
    __shared__ int   nb[DEG];
    __shared__ float rs[DEG];
    if (c < DEG) {
        int j = nbr[i * DEG + c];
        nb[c] = j;
        rs[c] = rsqrtf(deg[j]);
    }
    __syncthreads();
    float di  = deg[i];
    float rdi = rsqrtf(di);
    float acc = t[i * COLS + c] / di + bias[c];
#pragma unroll
    for (int k = 0; k < DEG; ++k)
        acc = fmaf(rdi * rs[k], t[nb[k] * COLS + c], acc);
    if (RELU) acc = fmaxf(acc, 0.0f);
    out[i * COLS + c] = acc;
}

// ---------------------------------------------------------------------------
// 5. out_feat[c] = sum_b h3[edge0_b, c] * h3[edge1_b, c]
// ---------------------------------------------------------------------------
__global__ void k_feat(const float* __restrict__ h3, const int* __restrict__ edge,
                       float* __restrict__ feat) {
    int c = threadIdx.x;  // 0..63
    float acc = 0.0f;
    for (int b = blockIdx.x; b < BATCH; b += gridDim.x) {
        int s = edge[b];
        int d = edge[BATCH + b];
        acc = fmaf(h3[s * F_OUT + c], h3[d * F_OUT + c], acc);
    }
    atomicAdd(&feat[c], acc);
}

// ---------------------------------------------------------------------------
// 6. structural path + final blend.  One block (128 thr) per batch edge.
//    out_struct[b] = sum_{i,j} w_src[i] w_dst[j] [src_nbr_i == dst_nbr_j]
// ---------------------------------------------------------------------------
__global__ __launch_bounds__(128) void k_struct(
    const int* __restrict__ edge, const int* __restrict__ nbr,
    const float* __restrict__ A_w, const float* __restrict__ nsf,
    const float* __restrict__ fn_w1, const float* __restrict__ fn_b1,
    const float* __restrict__ fn_w2, const float* __restrict__ fn_b2,
    const float* __restrict__ gp_w1, const float* __restrict__ gp_b1,
    const float* __restrict__ gp_w2, const float* __restrict__ gp_b2,
    const float* __restrict__ alpha, const float* __restrict__ feat,
    float* __restrict__ out) {
    int b   = blockIdx.x;
    int tid = threadIdx.x;
    __shared__ float wv[32];
    __shared__ int   nv[32];
    __shared__ float red[2];
    __shared__ float red2[2];

    // 32 entries (16 src-neighbors, 16 dst-neighbors); 4 threads per entry
    int e = tid >> 2, sub = tid & 3;
    int which = e >> 4, k = e & 15;
    int ref  = edge[which * BATCH + b];
    int node = nbr[ref * DEG + k];
    float v  = nsf[node];
    float part = 0.0f;
#pragma unroll
    for (int jj = 0; jj < FN_H / 4; ++jj) {
        int j = sub * (FN_H / 4) + jj;
        float hj = fmaf(v, fn_w1[j], fn_b1[j]);
        part = fmaf(fmaxf(hj, 0.0f), fn_w2[j], part);
    }
    part += __shfl_xor(part, 1);
    part += __shfl_xor(part, 2);
    if (sub == 0) {
        wv[e] = A_w[ref * DEG + k] * (part + fn_b2[0]);
        nv[e] = node;
    }
    __syncthreads();

    // 256 (i,j) pairs, 2 per thread
    float ps = 0.0f;
    {
        int p = tid, i0 = p >> 4, j0 = p & 15;
        if (nv[i0] == nv[16 + j0]) ps += wv[i0] * wv[16 + j0];
        p = tid + 128; i0 = p >> 4; j0 = p & 15;
        if (nv[i0] == nv[16 + j0]) ps += wv[i0] * wv[16 + j0];
    }
    for (int off = 1; off < 64; off <<= 1) ps += __shfl_xor(ps, off);
    if ((tid & 63) == 0) red[tid >> 6] = ps;
    __syncthreads();
    float os = red[0] + red[1];

    // gp MLP (GP_H = 128 = blockDim)
    float hj = fmaf(os, gp_w1[tid], gp_b1[tid]);
    float g  = fmaxf(hj, 0.0f) * gp_w2[tid];
    for (int off = 1; off < 64; off <<= 1) g += __shfl_xor(g, off);
    if ((tid & 63) == 0) red2[tid >> 6] = g;
    __syncthreads();
    float raw = red2[0] + red2[1] + gp_b2[0];
    float sig = 1.0f / (1.0f + expf(-raw));

    // softmax(alpha)
    float a0e = alpha[0], a1e = alpha[1];
    float m  = fmaxf(a0e, a1e);
    float e0 = expf(a0e - m), e1 = expf(a1e - m);
    float inv = 1.0f / (e0 + e1);
    float a0 = e0 * inv, a1 = e1 * inv;

    if (tid < F_OUT)
        out[b * F_OUT + tid] = fmaf(a1, feat[tid], a0 * sig) + 1e-15f;
    if (tid == 0) {
        out[BATCH * F_OUT + b] = sig;                          // out_struct_sig
        out[BATCH * F_OUT + BATCH + F_OUT + b] = raw;          // out_struct_raw
    }
    if (b == 0 && tid < F_OUT)
        out[BATCH * F_OUT + BATCH + tid] = feat[tid];          // out_feat
}

// ---------------------------------------------------------------------------
extern "C" void kernel_launch(void* const* d_in, const int* in_sizes, int n_in,
                              void* d_out, int out_size, void* d_ws, size_t ws_size,
                              hipStream_t stream) {
    const int*   edge  = (const int*)d_in[0];
    const float* x     = (const float*)d_in[1];
    const int*   nbr   = (const int*)d_in[2];
    const float* A_w   = (const float*)d_in[3];
    const float* W1    = (const float*)d_in[4];
    const float* b1    = (const float*)d_in[5];
    const float* W2    = (const float*)d_in[6];
    const float* b2    = (const float*)d_in[7];
    const float* W3    = (const float*)d_in[8];
    const float* b3    = (const float*)d_in[9];
    const float* fe_w1 = (const float*)d_in[10];
    const float* fe_b1 = (const float*)d_in[11];
    const float* fe_w2 = (const float*)d_in[12];
    const float* fe_b2 = (const float*)d_in[13];
    const float* fn_w1 = (const float*)d_in[14];
    const float* fn_b1 = (const float*)d_in[15];
    const float* fn_w2 = (const float*)d_in[16];
    const float* fn_b2 = (const float*)d_in[17];
    const float* gp_w1 = (const float*)d_in[18];
    const float* gp_b1 = (const float*)d_in[19];
    const float* gp_w2 = (const float*)d_in[20];
    const float* gp_b2 = (const float*)d_in[21];
    const float* alpha = (const float*)d_in[22];

    float* ws   = (float*)d_ws;
    float* deg  = ws;                       // N
    float* nsf  = deg + N_NODES;            // N
    float* tb   = nsf + N_NODES;            // N*128
    float* hb   = tb + N_NODES * HID;       // N*128
    float* feat = hb + N_NODES * HID;       // 64
    float* out  = (float*)d_out;

    k_init<<<(N_NODES + 255) / 256, 256, 0, stream>>>(deg, nsf, feat);
    k_edge<<<(E_TOT + 255) / 256, 256, 0, stream>>>(nbr, A_w, fe_w1, fe_b1,
                                                    fe_w2, fe_b2, deg, nsf);
    // GCN layer 1: t = x@W1 ; h = relu(agg)
    k_matmul<128><<<1024, 256, 0, stream>>>(x, W1, tb, N_NODES);
    k_agg<128, true><<<N_NODES, 128, 0, stream>>>(tb, nbr, deg, b1, hb);
    // GCN layer 2
    k_matmul<128><<<1024, 256, 0, stream>>>(hb, W2, tb, N_NODES);
    k_agg<128, true><<<N_NODES, 128, 0, stream>>>(tb, nbr, deg, b2, hb);
    // GCN layer 3 (128 -> 64, no relu)
    k_matmul<64><<<1024, 256, 0, stream>>>(hb, W3, tb, N_NODES);
    k_agg<64, false><<<N_NODES, 64, 0, stream>>>(tb, nbr, deg, b3, hb);
    // out_feat reduction over batch edges
    k_feat<<<256, 64, 0, stream>>>(hb, edge, feat);
    // structural path + final blend + all output writes
    k_struct<<<BATCH, 128, 0, stream>>>(edge, nbr, A_w, nsf,
                                        fn_w1, fn_b1, fn_w2, fn_b2,
                                        gp_w1, gp_b1, gp_w2, gp_b2,
                                        alpha, feat, out);
}

// Round 4
// 422.025 us; speedup vs baseline: 1.3372x; 1.3372x over previous
//
#include <hip/hip_runtime.h>
#include <math.h>

#define N_NODES 50000
#define MPAD    50048   // round up to 64-row GEMM tiles
#define DEG     16
#define BATCH   1024
#define F_IN    128
#define HID     128
#define F_OUT   64
#define FE_H    8
#define FN_H    128
#define GP_H    128
#define E_TOT   (N_NODES * DEG)

typedef __attribute__((ext_vector_type(8))) short  bf16x8;
typedef __attribute__((ext_vector_type(4))) float  f32x4;

__device__ __forceinline__ unsigned short f2bf(float f) {
    unsigned int u = __builtin_bit_cast(unsigned int, f);
    u += 0x7FFFu + ((u >> 16) & 1u);   // round-to-nearest-even
    return (unsigned short)(u >> 16);
}
__device__ __forceinline__ float bf2f(unsigned short s) {
    unsigned int u = ((unsigned int)s) << 16;
    return __builtin_bit_cast(float, u);
}

// ---------------------------------------------------------------------------
// 1. init: deg = 1.0 (self-loop), nsf = 0, feat accumulator = 0
// ---------------------------------------------------------------------------
__global__ void k_init(float* __restrict__ deg, float* __restrict__ nsf,
                       float* __restrict__ feat) {
    int i = blockIdx.x * blockDim.x + threadIdx.x;
    if (i < N_NODES) { deg[i] = 1.0f; nsf[i] = 0.0f; }
    if (i < F_OUT) feat[i] = 0.0f;
}

// ---------------------------------------------------------------------------
// 2. per-edge scatter: deg count and nsf += fe-MLP(A_w)
// ---------------------------------------------------------------------------
__global__ void k_edge(const int* __restrict__ nbr, const float* __restrict__ A_w,
                       const float* __restrict__ fe_w1, const float* __restrict__ fe_b1,
                       const float* __restrict__ fe_w2, const float* __restrict__ fe_b2,
                       float* __restrict__ deg, float* __restrict__ nsf) {
    int e = blockIdx.x * blockDim.x + threadIdx.x;
    if (e >= E_TOT) return;
    int   c = nbr[e];
    float v = A_w[e];
    float acc = fe_b2[0];
#pragma unroll
    for (int j = 0; j < FE_H; ++j) {
        float hj = fmaf(v, fe_w1[j], fe_b1[j]);
        acc = fmaf(fmaxf(hj, 0.0f), fe_w2[j], acc);
    }
    atomicAdd(&deg[c], 1.0f);
    atomicAdd(&nsf[c], acc);
}

// ---------------------------------------------------------------------------
// 3. rd = rsqrt(deg), idg = 1/deg   (after k_edge)
// ---------------------------------------------------------------------------
__global__ void k_rdeg(const float* __restrict__ deg, float* __restrict__ rd,
                       float* __restrict__ idg) {
    int i = blockIdx.x * blockDim.x + threadIdx.x;
    if (i < N_NODES) { float d = deg[i]; rd[i] = rsqrtf(d); idg[i] = 1.0f / d; }
}

// ---------------------------------------------------------------------------
// 4. convert x (f32 row-major) -> hb (bf16 row-major)
// ---------------------------------------------------------------------------
__global__ void k_cvt_x(const float* __restrict__ x, unsigned short* __restrict__ hb) {
    int i = blockIdx.x * blockDim.x + threadIdx.x;     // float4 index
    const int n4 = N_NODES * F_IN / 4;
    if (i >= n4) return;
    float4 v = ((const float4*)x)[i];
    ushort4 o;
    o.x = f2bf(v.x); o.y = f2bf(v.y); o.z = f2bf(v.z); o.w = f2bf(v.w);
    ((ushort4*)hb)[i] = o;
}

// ---------------------------------------------------------------------------
// 5. convert W [K=128][COLS] f32 -> Wt [COLS][128] bf16 (transposed)
// ---------------------------------------------------------------------------
__global__ void k_cvt_w(const float* __restrict__ W, unsigned short* __restrict__ Wt,
                        int cols) {
    int idx = blockIdx.x * blockDim.x + threadIdx.x;
    if (idx >= 128 * cols) return;
    int k = idx / cols, c = idx % cols;
    Wt[c * 128 + k] = f2bf(W[idx]);
}

// ---------------------------------------------------------------------------
// 6. GEMM  t[M,COLS] = hb[M,128] @ Wt^T   (bf16 MFMA, f32 out)
//    block = 256 thr = 4 waves; each wave does 16 rows x COLS; K-loop 4x32.
//    A frag: lane holds row (lane&15), k = ks*32 + (lane>>4)*8 + j  (16B load)
//    B frag: lane holds col (lane&15) of Wt, same k                 (16B load)
//    D frag: col = lane&15, row = (lane>>4)*4 + reg                 [m89]
// ---------------------------------------------------------------------------
template <int COLS>
__global__ __launch_bounds__(256) void k_gemm(const unsigned short* __restrict__ A,
                                              const unsigned short* __restrict__ Wt,
                                              float* __restrict__ t) {
    int lane = threadIdx.x & 63;
    int wave = threadIdx.x >> 6;
    int row_in = lane & 15;
    int kb = lane >> 4;                      // 0..3
    int r0 = blockIdx.x * 64 + wave * 16;    // grid covers MPAD/64 tiles exactly
    f32x4 acc[COLS / 16];
#pragma unroll
    for (int ct = 0; ct < COLS / 16; ++ct) acc[ct] = (f32x4){0.f, 0.f, 0.f, 0.f};
#pragma unroll
    for (int ks = 0; ks < 4; ++ks) {
        bf16x8 a = *(const bf16x8*)(A + (r0 + row_in) * 128 + ks * 32 + kb * 8);
#pragma unroll
        for (int ct = 0; ct < COLS / 16; ++ct) {
            bf16x8 b = *(const bf16x8*)(Wt + (ct * 16 + row_in) * 128 + ks * 32 + kb * 8);
            acc[ct] = __builtin_amdgcn_mfma_f32_16x16x32_bf16(a, b, acc[ct], 0, 0, 0);
        }
    }
#pragma unroll
    for (int ct = 0; ct < COLS / 16; ++ct)
#pragma unroll
        for (int r = 0; r < 4; ++r)
            t[(r0 + kb * 4 + r) * COLS + ct * 16 + row_in] = acc[ct][r];
}

// ---------------------------------------------------------------------------
// 7. aggregate: h[i,c] = relu?( sum_k rd_i rd_j t[j,c] + t[i,c]/d_i + b[c] )
//    float4 per thread; COLS/4 threads per node; writes bf16
// ---------------------------------------------------------------------------
template <int COLS, bool RELU>
__global__ __launch_bounds__(256) void k_agg(const float* __restrict__ t,
                                             const int* __restrict__ nbr,
                                             const float* __restrict__ rd,
                                             const float* __restrict__ idg,
                                             const float* __restrict__ bias,
                                             unsigned short* __restrict__ hout) {
    constexpr int TPN = COLS / 4;      // threads per node
    constexpr int NPB = 256 / TPN;     // nodes per block
    __shared__ int   s_nb[NPB][DEG];
    __shared__ float s_w[NPB][DEG];
    int g   = threadIdx.x / TPN;
    int sub = threadIdx.x % TPN;
    int i   = blockIdx.x * NPB + g;
    bool ok = (i < N_NODES);
    if (ok && sub < DEG) {
        int j = nbr[i * DEG + sub];
        s_nb[g][sub] = j;
        s_w[g][sub]  = rd[i] * rd[j];
    }
    __syncthreads();
    if (!ok) return;
    const float4* t4 = (const float4*)t;
    float4 bv = ((const float4*)bias)[sub];
    float  si = idg[i];
    float4 tv = t4[i * TPN + sub];
    float4 acc;
    acc.x = fmaf(tv.x, si, bv.x); acc.y = fmaf(tv.y, si, bv.y);
    acc.z = fmaf(tv.z, si, bv.z); acc.w = fmaf(tv.w, si, bv.w);
#pragma unroll
    for (int k = 0; k < DEG; ++k) {
        int   j = s_nb[g][k];
        float w = s_w[g][k];
        float4 v = t4[j * TPN + sub];
        acc.x = fmaf(w, v.x, acc.x); acc.y = fmaf(w, v.y, acc.y);
        acc.z = fmaf(w, v.z, acc.z); acc.w = fmaf(w, v.w, acc.w);
    }
    if (RELU) {
        acc.x = fmaxf(acc.x, 0.f); acc.y = fmaxf(acc.y, 0.f);
        acc.z = fmaxf(acc.z, 0.f); acc.w = fmaxf(acc.w, 0.f);
    }
    ushort4 o;
    o.x = f2bf(acc.x); o.y = f2bf(acc.y); o.z = f2bf(acc.z); o.w = f2bf(acc.w);
    ((ushort4*)hout)[i * TPN + sub] = o;
}

// ---------------------------------------------------------------------------
// 8. out_feat[c] = sum_b h3[e0_b,c] * h3[e1_b,c]   (h3 bf16)
// ---------------------------------------------------------------------------
__global__ void k_feat(const unsigned short* __restrict__ h3,
                       const int* __restrict__ edge, float* __restrict__ feat) {
    int c = threadIdx.x;  // 0..63
    float acc = 0.0f;
    for (int b = blockIdx.x; b < BATCH; b += gridDim.x) {
        int s = edge[b];
        int d = edge[BATCH + b];
        acc = fmaf(bf2f(h3[s * F_OUT + c]), bf2f(h3[d * F_OUT + c]), acc);
    }
    atomicAdd(&feat[c], acc);
}

// ---------------------------------------------------------------------------
// 9. structural path + final blend. One block (128 thr) per batch edge.
// ---------------------------------------------------------------------------
__global__ __launch_bounds__(128) void k_struct(
    const int* __restrict__ edge, const int* __restrict__ nbr,
    const float* __restrict__ A_w, const float* __restrict__ nsf,
    const float* __restrict__ fn_w1, const float* __restrict__ fn_b1,
    const float* __restrict__ fn_w2, const float* __restrict__ fn_b2,
    const float* __restrict__ gp_w1, const float* __restrict__ gp_b1,
    const float* __restrict__ gp_w2, const float* __restrict__ gp_b2,
    const float* __restrict__ alpha, const float* __restrict__ feat,
    float* __restrict__ out) {
    int b   = blockIdx.x;
    int tid = threadIdx.x;
    __shared__ float wv[32];
    __shared__ int   nv[32];
    __shared__ float red[2];
    __shared__ float red2[2];

    // 32 entries (16 src-nbrs, 16 dst-nbrs); 4 threads per entry share FN MLP
    int e = tid >> 2, sub = tid & 3;
    int which = e >> 4, k = e & 15;
    int ref  = edge[which * BATCH + b];
    int node = nbr[ref * DEG + k];
    float v  = nsf[node];
    float part = 0.0f;
#pragma unroll
    for (int jj = 0; jj < FN_H / 4; ++jj) {
        int j = sub * (FN_H / 4) + jj;
        float hj = fmaf(v, fn_w1[j], fn_b1[j]);
        part = fmaf(fmaxf(hj, 0.0f), fn_w2[j], part);
    }
    part += __shfl_xor(part, 1);
    part += __shfl_xor(part, 2);
    if (sub == 0) {
        wv[e] = A_w[ref * DEG + k] * (part + fn_b2[0]);
        nv[e] = node;
    }
    __syncthreads();

    // 256 (i,j) pairs, 2 per thread
    float ps = 0.0f;
    {
        int p = tid, i0 = p >> 4, j0 = p & 15;
        if (nv[i0] == nv[16 + j0]) ps += wv[i0] * wv[16 + j0];
        p = tid + 128; i0 = p >> 4; j0 = p & 15;
        if (nv[i0] == nv[16 + j0]) ps += wv[i0] * wv[16 + j0];
    }
    for (int off = 1; off < 64; off <<= 1) ps += __shfl_xor(ps, off);
    if ((tid & 63) == 0) red[tid >> 6] = ps;
    __syncthreads();
    float os = red[0] + red[1];

    // gp MLP (GP_H = 128 = blockDim)
    float hj = fmaf(os, gp_w1[tid], gp_b1[tid]);
    float g  = fmaxf(hj, 0.0f) * gp_w2[tid];
    for (int off = 1; off < 64; off <<= 1) g += __shfl_xor(g, off);
    if ((tid & 63) == 0) red2[tid >> 6] = g;
    __syncthreads();
    float raw = red2[0] + red2[1] + gp_b2[0];
    float sig = 1.0f / (1.0f + expf(-raw));

    float a0e = alpha[0], a1e = alpha[1];
    float m  = fmaxf(a0e, a1e);
    float e0 = expf(a0e - m), e1 = expf(a1e - m);
    float inv = 1.0f / (e0 + e1);
    float a0 = e0 * inv, a1 = e1 * inv;

    if (tid < F_OUT)
        out[b * F_OUT + tid] = fmaf(a1, feat[tid], a0 * sig) + 1e-15f;
    if (tid == 0) {
        out[BATCH * F_OUT + b] = sig;                          // out_struct_sig
        out[BATCH * F_OUT + BATCH + F_OUT + b] = raw;          // out_struct_raw
    }
    if (b == 0 && tid < F_OUT)
        out[BATCH * F_OUT + BATCH + tid] = feat[tid];          // out_feat
}

// ---------------------------------------------------------------------------
extern "C" void kernel_launch(void* const* d_in, const int* in_sizes, int n_in,
                              void* d_out, int out_size, void* d_ws, size_t ws_size,
                              hipStream_t stream) {
    const int*   edge  = (const int*)d_in[0];
    const float* x     = (const float*)d_in[1];
    const int*   nbr   = (const int*)d_in[2];
    const float* A_w   = (const float*)d_in[3];
    const float* W1    = (const float*)d_in[4];
    const float* b1    = (const float*)d_in[5];
    const float* W2    = (const float*)d_in[6];
    const float* b2    = (const float*)d_in[7];
    const float* W3    = (const float*)d_in[8];
    const float* b3    = (const float*)d_in[9];
    const float* fe_w1 = (const float*)d_in[10];
    const float* fe_b1 = (const float*)d_in[11];
    const float* fe_w2 = (const float*)d_in[12];
    const float* fe_b2 = (const float*)d_in[13];
    const float* fn_w1 = (const float*)d_in[14];
    const float* fn_b1 = (const float*)d_in[15];
    const float* fn_w2 = (const float*)d_in[16];
    const float* fn_b2 = (const float*)d_in[17];
    const float* gp_w1 = (const float*)d_in[18];
    const float* gp_b1 = (const float*)d_in[19];
    const float* gp_w2 = (const float*)d_in[20];
    const float* gp_b2 = (const float*)d_in[21];
    const float* alpha = (const float*)d_in[22];

    float* ws   = (float*)d_ws;
    float* deg  = ws;                        // N
    float* nsf  = deg + N_NODES;             // N
    float* rd   = nsf + N_NODES;             // N
    float* idg  = rd + N_NODES;              // N
    float* feat = idg + N_NODES;             // 64
    float* tb   = ws + 200064;               // MPAD*128 f32 (16B aligned)
    unsigned short* hb  = (unsigned short*)(tb + (size_t)MPAD * 128);  // MPAD*128 bf16
    unsigned short* Wt1 = hb + (size_t)MPAD * 128;                     // 128*128
    unsigned short* Wt2 = Wt1 + 128 * 128;                             // 128*128
    unsigned short* Wt3 = Wt2 + 128 * 128;                             // 64*128
    float* out  = (float*)d_out;

    k_init<<<(N_NODES + 255) / 256, 256, 0, stream>>>(deg, nsf, feat);
    k_edge<<<(E_TOT + 255) / 256, 256, 0, stream>>>(nbr, A_w, fe_w1, fe_b1,
                                                    fe_w2, fe_b2, deg, nsf);
    k_rdeg<<<(N_NODES + 255) / 256, 256, 0, stream>>>(deg, rd, idg);
    k_cvt_x<<<(N_NODES * F_IN / 4 + 255) / 256, 256, 0, stream>>>(x, hb);
    k_cvt_w<<<(128 * 128 + 255) / 256, 256, 0, stream>>>(W1, Wt1, 128);
    k_cvt_w<<<(128 * 128 + 255) / 256, 256, 0, stream>>>(W2, Wt2, 128);
    k_cvt_w<<<(128 * 64 + 255) / 256, 256, 0, stream>>>(W3, Wt3, 64);

    // GCN layer 1
    k_gemm<128><<<MPAD / 64, 256, 0, stream>>>(hb, Wt1, tb);
    k_agg<128, true><<<(N_NODES + 7) / 8, 256, 0, stream>>>(tb, nbr, rd, idg, b1, hb);
    // GCN layer 2
    k_gemm<128><<<MPAD / 64, 256, 0, stream>>>(hb, Wt2, tb);
    k_agg<128, true><<<(N_NODES + 7) / 8, 256, 0, stream>>>(tb, nbr, rd, idg, b2, hb);
    // GCN layer 3 (128 -> 64, no relu)
    k_gemm<64><<<MPAD / 64, 256, 0, stream>>>(hb, Wt3, tb);
    k_agg<64, false><<<(N_NODES + 15) / 16, 256, 0, stream>>>(tb, nbr, rd, idg, b3, hb);

    k_feat<<<256, 64, 0, stream>>>(hb, edge, feat);
    k_struct<<<BATCH, 128, 0, stream>>>(edge, nbr, A_w, nsf,
                                        fn_w1, fn_b1, fn_w2, fn_b2,
                                        gp_w1, gp_b1, gp_w2, gp_b2,
                                        alpha, feat, out);
}

// Round 5
// 302.020 us; speedup vs baseline: 1.8685x; 1.3973x over previous
//
#include <hip/hip_runtime.h>
#include <math.h>

#define N_NODES 50000
#define MPAD    50048   // round up to 64-row GEMM tiles
#define DEG     16
#define BATCH   1024
#define F_IN    128
#define HID     128
#define F_OUT   64
#define FE_H    8
#define FN_H    128
#define GP_H    128
#define E_TOT   (N_NODES * DEG)

typedef __attribute__((ext_vector_type(8))) short  bf16x8;
typedef __attribute__((ext_vector_type(4))) float  f32x4;
typedef unsigned long long u64;

__device__ __forceinline__ unsigned short f2bf(float f) {
    unsigned int u = __builtin_bit_cast(unsigned int, f);
    u += 0x7FFFu + ((u >> 16) & 1u);   // round-to-nearest-even
    return (unsigned short)(u >> 16);
}
__device__ __forceinline__ float bf2f(unsigned short s) {
    unsigned int u = ((unsigned int)s) << 16;
    return __builtin_bit_cast(float, u);
}

// ---------------------------------------------------------------------------
// 1. init: packed (count|nsf-fixed) = 0, feat accumulator = 0
// ---------------------------------------------------------------------------
__global__ void k_init(u64* __restrict__ packed, float* __restrict__ feat) {
    int i = blockIdx.x * blockDim.x + threadIdx.x;
    if (i < N_NODES) packed[i] = 0ull;
    if (i < F_OUT) feat[i] = 0.0f;
}

// ---------------------------------------------------------------------------
// 2. per-edge: ONE 64-bit atomic carrying (count += 1, nsf += fe-MLP(A_w)).
//    nsf fixed-point: bias 32, scale 2^19 (32*2^19 = 2^24 exactly).
// ---------------------------------------------------------------------------
__global__ void k_edge(const int* __restrict__ nbr, const float* __restrict__ A_w,
                       const float* __restrict__ fe_w1, const float* __restrict__ fe_b1,
                       const float* __restrict__ fe_w2, const float* __restrict__ fe_b2,
                       u64* __restrict__ packed) {
    int e = blockIdx.x * blockDim.x + threadIdx.x;
    if (e >= E_TOT) return;
    int   c = nbr[e];
    float v = A_w[e];
    float acc = fe_b2[0];
#pragma unroll
    for (int j = 0; j < FE_H; ++j) {
        float hj = fmaf(v, fe_w1[j], fe_b1[j]);
        acc = fmaf(fmaxf(hj, 0.0f), fe_w2[j], acc);
    }
    int fx = (int)rintf(fmaf(acc, 524288.0f, 16777216.0f));  // (acc+32)*2^19
    atomicAdd(&packed[c], (1ull << 32) + (u64)(unsigned int)fx);
}

// ---------------------------------------------------------------------------
// 3. unpack: rd = rsqrt(1+cnt), idg = 1/(1+cnt), nsf = (lo - cnt*2^24)/2^19
// ---------------------------------------------------------------------------
__global__ void k_unpack(const u64* __restrict__ packed, float* __restrict__ rd,
                         float* __restrict__ idg, float* __restrict__ nsf) {
    int i = blockIdx.x * blockDim.x + threadIdx.x;
    if (i >= N_NODES) return;
    u64 p = packed[i];
    unsigned int cnt = (unsigned int)(p >> 32);
    long long noBias = (long long)(p & 0xFFFFFFFFull) - ((long long)cnt << 24);
    float d = 1.0f + (float)cnt;
    rd[i]  = rsqrtf(d);
    idg[i] = 1.0f / d;
    nsf[i] = (float)noBias * (1.0f / 524288.0f);
}

// ---------------------------------------------------------------------------
// 4. convert x (f32 row-major) -> hb (bf16 row-major)
// ---------------------------------------------------------------------------
__global__ void k_cvt_x(const float* __restrict__ x, unsigned short* __restrict__ hb) {
    int i = blockIdx.x * blockDim.x + threadIdx.x;     // float4 index
    const int n4 = N_NODES * F_IN / 4;
    if (i >= n4) return;
    float4 v = ((const float4*)x)[i];
    ushort4 o;
    o.x = f2bf(v.x); o.y = f2bf(v.y); o.z = f2bf(v.z); o.w = f2bf(v.w);
    ((ushort4*)hb)[i] = o;
}

// ---------------------------------------------------------------------------
// 5. convert all three W [K][COLS] f32 -> Wt [COLS][128] bf16 (one launch)
// ---------------------------------------------------------------------------
__global__ void k_cvt_w3(const float* __restrict__ W1, const float* __restrict__ W2,
                         const float* __restrict__ W3, unsigned short* __restrict__ Wt1,
                         unsigned short* __restrict__ Wt2, unsigned short* __restrict__ Wt3) {
    int idx = blockIdx.x * blockDim.x + threadIdx.x;
    if (idx < 16384) {
        int k = idx >> 7, c = idx & 127;
        Wt1[c * 128 + k] = f2bf(W1[idx]);
    } else if (idx < 32768) {
        int t = idx - 16384; int k = t >> 7, c = t & 127;
        Wt2[c * 128 + k] = f2bf(W2[t]);
    } else if (idx < 40960) {
        int t = idx - 32768; int k = t >> 6, c = t & 63;
        Wt3[c * 128 + k] = f2bf(W3[t]);
    }
}

// ---------------------------------------------------------------------------
// 6. GEMM  t[M,COLS] = hb[M,128] @ Wt^T   (bf16 MFMA, bf16 out)
//    A frag: lane holds row (lane&15), k = ks*32 + (lane>>4)*8 + j
//    D frag: col = lane&15, row = (lane>>4)*4 + reg                 [m89]
// ---------------------------------------------------------------------------
template <int COLS>
__global__ __launch_bounds__(256) void k_gemm(const unsigned short* __restrict__ A,
                                              const unsigned short* __restrict__ Wt,
                                              unsigned short* __restrict__ t) {
    int lane = threadIdx.x & 63;
    int wave = threadIdx.x >> 6;
    int row_in = lane & 15;
    int kb = lane >> 4;                      // 0..3
    int r0 = blockIdx.x * 64 + wave * 16;    // grid covers MPAD/64 tiles exactly
    f32x4 acc[COLS / 16];
#pragma unroll
    for (int ct = 0; ct < COLS / 16; ++ct) acc[ct] = (f32x4){0.f, 0.f, 0.f, 0.f};
#pragma unroll
    for (int ks = 0; ks < 4; ++ks) {
        bf16x8 a = *(const bf16x8*)(A + (r0 + row_in) * 128 + ks * 32 + kb * 8);
#pragma unroll
        for (int ct = 0; ct < COLS / 16; ++ct) {
            bf16x8 b = *(const bf16x8*)(Wt + (ct * 16 + row_in) * 128 + ks * 32 + kb * 8);
            acc[ct] = __builtin_amdgcn_mfma_f32_16x16x32_bf16(a, b, acc[ct], 0, 0, 0);
        }
    }
#pragma unroll
    for (int ct = 0; ct < COLS / 16; ++ct)
#pragma unroll
        for (int r = 0; r < 4; ++r)
            t[(r0 + kb * 4 + r) * COLS + ct * 16 + row_in] = f2bf(acc[ct][r]);
}

// ---------------------------------------------------------------------------
// 7. aggregate: h[i,c] = relu?( sum_k rd_i rd_j t[j,c] + t[i,c]/d_i + b[c] )
//    t is bf16; ushort4 (4 cols) per thread; COLS/4 threads per node
// ---------------------------------------------------------------------------
template <int COLS, bool RELU>
__global__ __launch_bounds__(256) void k_agg(const unsigned short* __restrict__ t,
                                             const int* __restrict__ nbr,
                                             const float* __restrict__ rd,
                                             const float* __restrict__ idg,
                                             const float* __restrict__ bias,
                                             unsigned short* __restrict__ hout) {
    constexpr int TPN = COLS / 4;      // threads per node
    constexpr int NPB = 256 / TPN;     // nodes per block
    __shared__ int   s_nb[NPB][DEG];
    __shared__ float s_w[NPB][DEG];
    int g   = threadIdx.x / TPN;
    int sub = threadIdx.x % TPN;
    int i   = blockIdx.x * NPB + g;
    bool ok = (i < N_NODES);
    if (ok && sub < DEG) {
        int j = nbr[i * DEG + sub];
        s_nb[g][sub] = j;
        s_w[g][sub]  = rd[i] * rd[j];
    }
    __syncthreads();
    if (!ok) return;
    const ushort4* t4 = (const ushort4*)t;
    float4 bv = ((const float4*)bias)[sub];
    float  si = idg[i];
    ushort4 tv = t4[i * TPN + sub];
    float4 acc;
    acc.x = fmaf(bf2f(tv.x), si, bv.x); acc.y = fmaf(bf2f(tv.y), si, bv.y);
    acc.z = fmaf(bf2f(tv.z), si, bv.z); acc.w = fmaf(bf2f(tv.w), si, bv.w);
#pragma unroll
    for (int k = 0; k < DEG; ++k) {
        int   j = s_nb[g][k];
        float w = s_w[g][k];
        ushort4 v = t4[j * TPN + sub];
        acc.x = fmaf(w, bf2f(v.x), acc.x); acc.y = fmaf(w, bf2f(v.y), acc.y);
        acc.z = fmaf(w, bf2f(v.z), acc.z); acc.w = fmaf(w, bf2f(v.w), acc.w);
    }
    if (RELU) {
        acc.x = fmaxf(acc.x, 0.f); acc.y = fmaxf(acc.y, 0.f);
        acc.z = fmaxf(acc.z, 0.f); acc.w = fmaxf(acc.w, 0.f);
    }
    ushort4 o;
    o.x = f2bf(acc.x); o.y = f2bf(acc.y); o.z = f2bf(acc.z); o.w = f2bf(acc.w);
    ((ushort4*)hout)[i * TPN + sub] = o;
}

// ---------------------------------------------------------------------------
// 8. out_feat[c] = sum_b h3[e0_b,c] * h3[e1_b,c]   (h3 bf16)
// ---------------------------------------------------------------------------
__global__ void k_feat(const unsigned short* __restrict__ h3,
                       const int* __restrict__ edge, float* __restrict__ feat) {
    int c = threadIdx.x;  // 0..63
    float acc = 0.0f;
    for (int b = blockIdx.x; b < BATCH; b += gridDim.x) {
        int s = edge[b];
        int d = edge[BATCH + b];
        acc = fmaf(bf2f(h3[s * F_OUT + c]), bf2f(h3[d * F_OUT + c]), acc);
    }
    atomicAdd(&feat[c], acc);
}

// ---------------------------------------------------------------------------
// 9. structural path + final blend. One block (128 thr) per batch edge.
// ---------------------------------------------------------------------------
__global__ __launch_bounds__(128) void k_struct(
    const int* __restrict__ edge, const int* __restrict__ nbr,
    const float* __restrict__ A_w, const float* __restrict__ nsf,
    const float* __restrict__ fn_w1, const float* __restrict__ fn_b1,
    const float* __restrict__ fn_w2, const float* __restrict__ fn_b2,
    const float* __restrict__ gp_w1, const float* __restrict__ gp_b1,
    const float* __restrict__ gp_w2, const float* __restrict__ gp_b2,
    const float* __restrict__ alpha, const float* __restrict__ feat,
    float* __restrict__ out) {
    int b   = blockIdx.x;
    int tid = threadIdx.x;
    __shared__ float wv[32];
    __shared__ int   nv[32];
    __shared__ float red[2];
    __shared__ float red2[2];

    // 32 entries (16 src-nbrs, 16 dst-nbrs); 4 threads per entry share FN MLP
    int e = tid >> 2, sub = tid & 3;
    int which = e >> 4, k = e & 15;
    int ref  = edge[which * BATCH + b];
    int node = nbr[ref * DEG + k];
    float v  = nsf[node];
    float part = 0.0f;
#pragma unroll
    for (int jj = 0; jj < FN_H / 4; ++jj) {
        int j = sub * (FN_H / 4) + jj;
        float hj = fmaf(v, fn_w1[j], fn_b1[j]);
        part = fmaf(fmaxf(hj, 0.0f), fn_w2[j], part);
    }
    part += __shfl_xor(part, 1);
    part += __shfl_xor(part, 2);
    if (sub == 0) {
        wv[e] = A_w[ref * DEG + k] * (part + fn_b2[0]);
        nv[e] = node;
    }
    __syncthreads();

    // 256 (i,j) pairs, 2 per thread
    float ps = 0.0f;
    {
        int p = tid, i0 = p >> 4, j0 = p & 15;
        if (nv[i0] == nv[16 + j0]) ps += wv[i0] * wv[16 + j0];
        p = tid + 128; i0 = p >> 4; j0 = p & 15;
        if (nv[i0] == nv[16 + j0]) ps += wv[i0] * wv[16 + j0];
    }
    for (int off = 1; off < 64; off <<= 1) ps += __shfl_xor(ps, off);
    if ((tid & 63) == 0) red[tid >> 6] = ps;
    __syncthreads();
    float os = red[0] + red[1];

    // gp MLP (GP_H = 128 = blockDim)
    float hj = fmaf(os, gp_w1[tid], gp_b1[tid]);
    float g  = fmaxf(hj, 0.0f) * gp_w2[tid];
    for (int off = 1; off < 64; off <<= 1) g += __shfl_xor(g, off);
    if ((tid & 63) == 0) red2[tid >> 6] = g;
    __syncthreads();
    float raw = red2[0] + red2[1] + gp_b2[0];
    float sig = 1.0f / (1.0f + expf(-raw));

    float a0e = alpha[0], a1e = alpha[1];
    float m  = fmaxf(a0e, a1e);
    float e0 = expf(a0e - m), e1 = expf(a1e - m);
    float inv = 1.0f / (e0 + e1);
    float a0 = e0 * inv, a1 = e1 * inv;

    if (tid < F_OUT)
        out[b * F_OUT + tid] = fmaf(a1, feat[tid], a0 * sig) + 1e-15f;
    if (tid == 0) {
        out[BATCH * F_OUT + b] = sig;                          // out_struct_sig
        out[BATCH * F_OUT + BATCH + F_OUT + b] = raw;          // out_struct_raw
    }
    if (b == 0 && tid < F_OUT)
        out[BATCH * F_OUT + BATCH + tid] = feat[tid];          // out_feat
}

// ---------------------------------------------------------------------------
extern "C" void kernel_launch(void* const* d_in, const int* in_sizes, int n_in,
                              void* d_out, int out_size, void* d_ws, size_t ws_size,
                              hipStream_t stream) {
    const int*   edge  = (const int*)d_in[0];
    const float* x     = (const float*)d_in[1];
    const int*   nbr   = (const int*)d_in[2];
    const float* A_w   = (const float*)d_in[3];
    const float* W1    = (const float*)d_in[4];
    const float* b1    = (const float*)d_in[5];
    const float* W2    = (const float*)d_in[6];
    const float* b2    = (const float*)d_in[7];
    const float* W3    = (const float*)d_in[8];
    const float* b3    = (const float*)d_in[9];
    const float* fe_w1 = (const float*)d_in[10];
    const float* fe_b1 = (const float*)d_in[11];
    const float* fe_w2 = (const float*)d_in[12];
    const float* fe_b2 = (const float*)d_in[13];
    const float* fn_w1 = (const float*)d_in[14];
    const float* fn_b1 = (const float*)d_in[15];
    const float* fn_w2 = (const float*)d_in[16];
    const float* fn_b2 = (const float*)d_in[17];
    const float* gp_w1 = (const float*)d_in[18];
    const float* gp_b1 = (const float*)d_in[19];
    const float* gp_w2 = (const float*)d_in[20];
    const float* gp_b2 = (const float*)d_in[21];
    const float* alpha = (const float*)d_in[22];

    char* w = (char*)d_ws;
    u64*   packed = (u64*)w;                        // 50000 * 8 = 400000 B
    float* rd     = (float*)(w + 400000);           // 200000 B
    float* idg    = (float*)(w + 600000);           // 200000 B
    float* nsf    = (float*)(w + 800000);           // 200000 B
    float* feat   = (float*)(w + 1000000);          // 256 B
    unsigned short* tb  = (unsigned short*)(w + 1000448);          // MPAD*128 bf16
    unsigned short* hb  = tb + (size_t)MPAD * 128;                 // MPAD*128 bf16
    unsigned short* Wt1 = hb + (size_t)MPAD * 128;                 // 128*128
    unsigned short* Wt2 = Wt1 + 128 * 128;                         // 128*128
    unsigned short* Wt3 = Wt2 + 128 * 128;                         // 64*128
    float* out  = (float*)d_out;

    k_init<<<(N_NODES + 255) / 256, 256, 0, stream>>>(packed, feat);
    k_edge<<<(E_TOT + 255) / 256, 256, 0, stream>>>(nbr, A_w, fe_w1, fe_b1,
                                                    fe_w2, fe_b2, packed);
    k_unpack<<<(N_NODES + 255) / 256, 256, 0, stream>>>(packed, rd, idg, nsf);
    k_cvt_x<<<(N_NODES * F_IN / 4 + 255) / 256, 256, 0, stream>>>(x, hb);
    k_cvt_w3<<<(40960 + 255) / 256, 256, 0, stream>>>(W1, W2, W3, Wt1, Wt2, Wt3);

    // GCN layer 1
    k_gemm<128><<<MPAD / 64, 256, 0, stream>>>(hb, Wt1, tb);
    k_agg<128, true><<<(N_NODES + 7) / 8, 256, 0, stream>>>(tb, nbr, rd, idg, b1, hb);
    // GCN layer 2
    k_gemm<128><<<MPAD / 64, 256, 0, stream>>>(hb, Wt2, tb);
    k_agg<128, true><<<(N_NODES + 7) / 8, 256, 0, stream>>>(tb, nbr, rd, idg, b2, hb);
    // GCN layer 3 (128 -> 64, no relu)
    k_gemm<64><<<MPAD / 64, 256, 0, stream>>>(hb, Wt3, tb);
    k_agg<64, false><<<(N_NODES + 15) / 16, 256, 0, stream>>>(tb, nbr, rd, idg, b3, hb);

    k_feat<<<256, 64, 0, stream>>>(hb, edge, feat);
    k_struct<<<BATCH, 128, 0, stream>>>(edge, nbr, A_w, nsf,
                                        fn_w1, fn_b1, fn_w2, fn_b2,
                                        gp_w1, gp_b1, gp_w2, gp_b2,
                                        alpha, feat, out);
}

// Round 7
// 280.203 us; speedup vs baseline: 2.0139x; 1.0779x over previous
//
#include <hip/hip_runtime.h>
#include <math.h>

#define N_NODES 50000
#define MPAD    50048   // round up to 64-row GEMM tiles
#define DEG     16
#define BATCH   1024
#define F_IN    128
#define HID     128
#define F_OUT   64
#define FE_H    8
#define FN_H    128
#define GP_H    128
#define E_TOT   (N_NODES * DEG)
#define GEMM1_BLOCKS (MPAD / 64)            // 782
#define EDGE_BLOCKS  ((E_TOT + 255) / 256)  // 3125

typedef __attribute__((ext_vector_type(8))) short          bf16x8;
typedef __attribute__((ext_vector_type(8))) unsigned short u16x8;
typedef __attribute__((ext_vector_type(4))) float          f32x4;
typedef unsigned long long u64;

__device__ __forceinline__ unsigned short f2bf(float f) {
    unsigned int u = __builtin_bit_cast(unsigned int, f);
    u += 0x7FFFu + ((u >> 16) & 1u);   // round-to-nearest-even
    return (unsigned short)(u >> 16);
}
__device__ __forceinline__ float bf2f(unsigned short s) {
    unsigned int u = ((unsigned int)s) << 16;
    return __builtin_bit_cast(float, u);
}
__device__ __forceinline__ float pdeg(u64 p) {   // d = 1 + count
    return 1.0f + (float)(unsigned int)(p >> 32);
}

// ---------------------------------------------------------------------------
// 1. prep: zero packed/feat, convert W1/W2/W3 -> transposed bf16
// ---------------------------------------------------------------------------
__global__ void k_prep(u64* __restrict__ packed, float* __restrict__ feat,
                       const float* __restrict__ W1, const float* __restrict__ W2,
                       const float* __restrict__ W3, unsigned short* __restrict__ Wt1,
                       unsigned short* __restrict__ Wt2, unsigned short* __restrict__ Wt3) {
    int idx = blockIdx.x * blockDim.x + threadIdx.x;
    if (idx < N_NODES) packed[idx] = 0ull;
    if (idx < F_OUT) feat[idx] = 0.0f;
    if (idx < 16384) {
        int k = idx >> 7, c = idx & 127;
        Wt1[c * 128 + k] = f2bf(W1[idx]);
    } else if (idx < 32768) {
        int t = idx - 16384; int k = t >> 7, c = t & 127;
        Wt2[c * 128 + k] = f2bf(W2[t]);
    } else if (idx < 40960) {
        int t = idx - 32768; int k = t >> 6, c = t & 63;
        Wt3[c * 128 + k] = f2bf(W3[t]);
    }
}

// ---------------------------------------------------------------------------
// 2. FUSED: layer-1 GEMM (f32 A read, bf16 MFMA) ∥ edge-atomic scatter.
//    Blocks [0,GEMM1_BLOCKS): t = x@W1.  Blocks after: packed atomics.
//    A frag: lane holds row (lane&15), k = ks*32 + (lane>>4)*8 + j
//    D frag: col = lane&15, row = (lane>>4)*4 + reg                 [m89]
// ---------------------------------------------------------------------------
__global__ __launch_bounds__(256) void k_gemm1_edge(
    const float* __restrict__ x, const unsigned short* __restrict__ Wt,
    unsigned short* __restrict__ t,
    const int* __restrict__ nbr, const float* __restrict__ A_w,
    const float* __restrict__ fe_w1, const float* __restrict__ fe_b1,
    const float* __restrict__ fe_w2, const float* __restrict__ fe_b2,
    u64* __restrict__ packed) {
    if (blockIdx.x < GEMM1_BLOCKS) {
        int lane = threadIdx.x & 63;
        int wave = threadIdx.x >> 6;
        int row_in = lane & 15;
        int kb = lane >> 4;                      // 0..3
        int r0 = blockIdx.x * 64 + wave * 16;
        int r  = min(r0 + row_in, N_NODES - 1);  // clamp: no OOB read of x
        f32x4 acc[8];
#pragma unroll
        for (int ct = 0; ct < 8; ++ct) acc[ct] = (f32x4){0.f, 0.f, 0.f, 0.f};
#pragma unroll
        for (int ks = 0; ks < 4; ++ks) {
            const float4* xr = (const float4*)(x + r * 128 + ks * 32 + kb * 8);
            float4 p0 = xr[0], p1 = xr[1];
            bf16x8 a;
            a[0] = (short)f2bf(p0.x); a[1] = (short)f2bf(p0.y);
            a[2] = (short)f2bf(p0.z); a[3] = (short)f2bf(p0.w);
            a[4] = (short)f2bf(p1.x); a[5] = (short)f2bf(p1.y);
            a[6] = (short)f2bf(p1.z); a[7] = (short)f2bf(p1.w);
#pragma unroll
            for (int ct = 0; ct < 8; ++ct) {
                bf16x8 b = *(const bf16x8*)(Wt + (ct * 16 + row_in) * 128 + ks * 32 + kb * 8);
                acc[ct] = __builtin_amdgcn_mfma_f32_16x16x32_bf16(a, b, acc[ct], 0, 0, 0);
            }
        }
#pragma unroll
        for (int ct = 0; ct < 8; ++ct)
#pragma unroll
            for (int rr = 0; rr < 4; ++rr)
                t[(r0 + kb * 4 + rr) * 128 + ct * 16 + row_in] = f2bf(acc[ct][rr]);
    } else {
        int e = (blockIdx.x - GEMM1_BLOCKS) * 256 + threadIdx.x;
        if (e >= E_TOT) return;
        int   c = nbr[e];
        float v = A_w[e];
        float acc = fe_b2[0];
#pragma unroll
        for (int j = 0; j < FE_H; ++j) {
            float hj = fmaf(v, fe_w1[j], fe_b1[j]);
            acc = fmaf(fmaxf(hj, 0.0f), fe_w2[j], acc);
        }
        // fixed-point: bias 32, scale 2^19 (32*2^19 = 2^24 exactly)
        int fx = (int)rintf(fmaf(acc, 524288.0f, 16777216.0f));
        atomicAdd(&packed[c], (1ull << 32) + (u64)(unsigned int)fx);
    }
}

// ---------------------------------------------------------------------------
// 3. GEMM  t[M,COLS] = hb[M,128] @ Wt^T   (bf16 A, bf16 out)
// ---------------------------------------------------------------------------
template <int COLS>
__global__ __launch_bounds__(256) void k_gemm(const unsigned short* __restrict__ A,
                                              const unsigned short* __restrict__ Wt,
                                              unsigned short* __restrict__ t) {
    int lane = threadIdx.x & 63;
    int wave = threadIdx.x >> 6;
    int row_in = lane & 15;
    int kb = lane >> 4;
    int r0 = blockIdx.x * 64 + wave * 16;
    f32x4 acc[COLS / 16];
#pragma unroll
    for (int ct = 0; ct < COLS / 16; ++ct) acc[ct] = (f32x4){0.f, 0.f, 0.f, 0.f};
#pragma unroll
    for (int ks = 0; ks < 4; ++ks) {
        bf16x8 a = *(const bf16x8*)(A + (r0 + row_in) * 128 + ks * 32 + kb * 8);
#pragma unroll
        for (int ct = 0; ct < COLS / 16; ++ct) {
            bf16x8 b = *(const bf16x8*)(Wt + (ct * 16 + row_in) * 128 + ks * 32 + kb * 8);
            acc[ct] = __builtin_amdgcn_mfma_f32_16x16x32_bf16(a, b, acc[ct], 0, 0, 0);
        }
    }
#pragma unroll
    for (int ct = 0; ct < COLS / 16; ++ct)
#pragma unroll
        for (int r = 0; r < 4; ++r)
            t[(r0 + kb * 4 + r) * COLS + ct * 16 + row_in] = f2bf(acc[ct][r]);
}

// ---------------------------------------------------------------------------
// 4. aggregate: h[i,c] = relu?( sum_k rsqrt(d_i d_j) t[j,c] + t[i,c]/d_i + b[c] )
//    16B/lane gathers; deg decoded inline from packed.
// ---------------------------------------------------------------------------
template <int COLS, bool RELU>
__global__ __launch_bounds__(256) void k_agg(const unsigned short* __restrict__ t,
                                             const int* __restrict__ nbr,
                                             const u64* __restrict__ packed,
                                             const float* __restrict__ bias,
                                             unsigned short* __restrict__ hout) {
    constexpr int TPN = COLS / 8;      // threads per node (16B each)
    constexpr int NPB = 256 / TPN;     // nodes per block
    __shared__ int   s_nb[NPB][DEG];
    __shared__ float s_w[NPB][DEG];
    int g   = threadIdx.x / TPN;
    int sub = threadIdx.x % TPN;
    int i   = blockIdx.x * NPB + g;
    bool ok = (i < N_NODES);
    if (ok) {
        float di = pdeg(packed[i]);
        for (int k = sub; k < DEG; k += TPN) {
            int j = nbr[i * DEG + k];
            s_nb[g][k] = j;
            s_w[g][k]  = rsqrtf(di * pdeg(packed[j]));   // matches ref rsqrt(d_i*d_j)
        }
    }
    __syncthreads();
    if (!ok) return;
    const u16x8* t8 = (const u16x8*)t;
    float si = 1.0f / pdeg(packed[i]);
    float4 b0 = ((const float4*)bias)[sub * 2];
    float4 b1 = ((const float4*)bias)[sub * 2 + 1];
    float bv[8] = {b0.x, b0.y, b0.z, b0.w, b1.x, b1.y, b1.z, b1.w};
    u16x8 tv = t8[i * TPN + sub];
    float acc[8];
#pragma unroll
    for (int c = 0; c < 8; ++c) acc[c] = fmaf(bf2f((unsigned short)tv[c]), si, bv[c]);
#pragma unroll
    for (int k = 0; k < DEG; ++k) {
        int   j = s_nb[g][k];
        float w = s_w[g][k];
        u16x8 v = t8[j * TPN + sub];
#pragma unroll
        for (int c = 0; c < 8; ++c) acc[c] = fmaf(w, bf2f((unsigned short)v[c]), acc[c]);
    }
    u16x8 o;
#pragma unroll
    for (int c = 0; c < 8; ++c) {
        float a = RELU ? fmaxf(acc[c], 0.0f) : acc[c];
        o[c] = f2bf(a);
    }
    ((u16x8*)hout)[i * TPN + sub] = o;
}

// ---------------------------------------------------------------------------
// 5. out_feat[c] = sum_b h3[e0_b,c] * h3[e1_b,c]   (h3 bf16)
// ---------------------------------------------------------------------------
__global__ void k_feat(const unsigned short* __restrict__ h3,
                       const int* __restrict__ edge, float* __restrict__ feat) {
    int c = threadIdx.x;  // 0..63
    float acc = 0.0f;
    for (int b = blockIdx.x; b < BATCH; b += gridDim.x) {
        int s = edge[b];
        int d = edge[BATCH + b];
        acc = fmaf(bf2f(h3[s * F_OUT + c]), bf2f(h3[d * F_OUT + c]), acc);
    }
    atomicAdd(&feat[c], acc);
}

// ---------------------------------------------------------------------------
// 6. structural path + final blend. One block (128 thr) per batch edge.
//    nsf decoded inline from packed.
// ---------------------------------------------------------------------------
__global__ __launch_bounds__(128) void k_struct(
    const int* __restrict__ edge, const int* __restrict__ nbr,
    const float* __restrict__ A_w, const u64* __restrict__ packed,
    const float* __restrict__ fn_w1, const float* __restrict__ fn_b1,
    const float* __restrict__ fn_w2, const float* __restrict__ fn_b2,
    const float* __restrict__ gp_w1, const float* __restrict__ gp_b1,
    const float* __restrict__ gp_w2, const float* __restrict__ gp_b2,
    const float* __restrict__ alpha, const float* __restrict__ feat,
    float* __restrict__ out) {
    int b   = blockIdx.x;
    int tid = threadIdx.x;
    __shared__ float wv[32];
    __shared__ int   nv[32];
    __shared__ float red[2];
    __shared__ float red2[2];

    // 32 entries (16 src-nbrs, 16 dst-nbrs); 4 threads per entry share FN MLP
    int e = tid >> 2, sub = tid & 3;
    int which = e >> 4, k = e & 15;
    int ref  = edge[which * BATCH + b];
    int node = nbr[ref * DEG + k];
    u64  p   = packed[node];
    unsigned int cnt = (unsigned int)(p >> 32);
    long long noBias = (long long)(p & 0xFFFFFFFFull) - ((long long)cnt << 24);
    float v = (float)noBias * (1.0f / 524288.0f);    // nsf[node]
    float part = 0.0f;
#pragma unroll
    for (int jj = 0; jj < FN_H / 4; ++jj) {
        int j = sub * (FN_H / 4) + jj;
        float hj = fmaf(v, fn_w1[j], fn_b1[j]);
        part = fmaf(fmaxf(hj, 0.0f), fn_w2[j], part);
    }
    part += __shfl_xor(part, 1);
    part += __shfl_xor(part, 2);
    if (sub == 0) {
        wv[e] = A_w[ref * DEG + k] * (part + fn_b2[0]);
        nv[e] = node;
    }
    __syncthreads();

    // 256 (i,j) pairs, 2 per thread
    float ps = 0.0f;
    {
        int p2 = tid, i0 = p2 >> 4, j0 = p2 & 15;
        if (nv[i0] == nv[16 + j0]) ps += wv[i0] * wv[16 + j0];
        p2 = tid + 128; i0 = p2 >> 4; j0 = p2 & 15;
        if (nv[i0] == nv[16 + j0]) ps += wv[i0] * wv[16 + j0];
    }
    for (int off = 1; off < 64; off <<= 1) ps += __shfl_xor(ps, off);
    if ((tid & 63) == 0) red[tid >> 6] = ps;
    __syncthreads();
    float os = red[0] + red[1];

    // gp MLP (GP_H = 128 = blockDim)
    float hj = fmaf(os, gp_w1[tid], gp_b1[tid]);
    float g  = fmaxf(hj, 0.0f) * gp_w2[tid];
    for (int off = 1; off < 64; off <<= 1) g += __shfl_xor(g, off);
    if ((tid & 63) == 0) red2[tid >> 6] = g;
    __syncthreads();
    float raw = red2[0] + red2[1] + gp_b2[0];
    float sig = 1.0f / (1.0f + expf(-raw));

    float a0e = alpha[0], a1e = alpha[1];
    float m  = fmaxf(a0e, a1e);
    float e0 = expf(a0e - m), e1 = expf(a1e - m);
    float inv = 1.0f / (e0 + e1);
    float a0 = e0 * inv, a1 = e1 * inv;

    if (tid < F_OUT)
        out[b * F_OUT + tid] = fmaf(a1, feat[tid], a0 * sig) + 1e-15f;
    if (tid == 0) {
        out[BATCH * F_OUT + b] = sig;                          // out_struct_sig
        out[BATCH * F_OUT + BATCH + F_OUT + b] = raw;          // out_struct_raw
    }
    if (b == 0 && tid < F_OUT)
        out[BATCH * F_OUT + BATCH + tid] = feat[tid];          // out_feat
}

// ---------------------------------------------------------------------------
extern "C" void kernel_launch(void* const* d_in, const int* in_sizes, int n_in,
                              void* d_out, int out_size, void* d_ws, size_t ws_size,
                              hipStream_t stream) {
    const int*   edge  = (const int*)d_in[0];
    const float* x     = (const float*)d_in[1];
    const int*   nbr   = (const int*)d_in[2];
    const float* A_w   = (const float*)d_in[3];
    const float* W1    = (const float*)d_in[4];
    const float* b1    = (const float*)d_in[5];
    const float* W2    = (const float*)d_in[6];
    const float* b2    = (const float*)d_in[7];
    const float* W3    = (const float*)d_in[8];
    const float* b3    = (const float*)d_in[9];
    const float* fe_w1 = (const float*)d_in[10];
    const float* fe_b1 = (const float*)d_in[11];
    const float* fe_w2 = (const float*)d_in[12];
    const float* fe_b2 = (const float*)d_in[13];
    const float* fn_w1 = (const float*)d_in[14];
    const float* fn_b1 = (const float*)d_in[15];
    const float* fn_w2 = (const float*)d_in[16];
    const float* fn_b2 = (const float*)d_in[17];
    const float* gp_w1 = (const float*)d_in[18];
    const float* gp_b1 = (const float*)d_in[19];
    const float* gp_w2 = (const float*)d_in[20];
    const float* gp_b2 = (const float*)d_in[21];
    const float* alpha = (const float*)d_in[22];

    char* w = (char*)d_ws;
    u64*   packed = (u64*)w;                                       // 400000 B
    float* feat   = (float*)(w + 400000);                          // 256 B
    unsigned short* tb  = (unsigned short*)(w + 400256);           // MPAD*128 bf16
    unsigned short* hb  = tb + (size_t)MPAD * 128;                 // MPAD*128 bf16
    unsigned short* Wt1 = hb + (size_t)MPAD * 128;                 // 128*128
    unsigned short* Wt2 = Wt1 + 128 * 128;                         // 128*128
    unsigned short* Wt3 = Wt2 + 128 * 128;                         // 64*128
    float* out  = (float*)d_out;

    k_prep<<<(N_NODES + 255) / 256, 256, 0, stream>>>(packed, feat, W1, W2, W3,
                                                      Wt1, Wt2, Wt3);
    // layer-1 GEMM ∥ edge scatter (independent work, one launch)
    k_gemm1_edge<<<GEMM1_BLOCKS + EDGE_BLOCKS, 256, 0, stream>>>(
        x, Wt1, tb, nbr, A_w, fe_w1, fe_b1, fe_w2, fe_b2, packed);
    k_agg<128, true><<<(N_NODES + 15) / 16, 256, 0, stream>>>(tb, nbr, packed, b1, hb);
    // GCN layer 2
    k_gemm<128><<<MPAD / 64, 256, 0, stream>>>(hb, Wt2, tb);
    k_agg<128, true><<<(N_NODES + 15) / 16, 256, 0, stream>>>(tb, nbr, packed, b2, hb);
    // GCN layer 3 (128 -> 64, no relu)
    k_gemm<64><<<MPAD / 64, 256, 0, stream>>>(hb, Wt3, tb);
    k_agg<64, false><<<(N_NODES + 31) / 32, 256, 0, stream>>>(tb, nbr, packed, b3, hb);

    k_feat<<<256, 64, 0, stream>>>(hb, edge, feat);
    k_struct<<<BATCH, 128, 0, stream>>>(edge, nbr, A_w, packed,
                                        fn_w1, fn_b1, fn_w2, fn_b2,
                                        gp_w1, gp_b1, gp_w2, gp_b2,
                                        alpha, feat, out);
}

// Round 8
// 271.367 us; speedup vs baseline: 2.0795x; 1.0326x over previous
//
#include <hip/hip_runtime.h>
#include <math.h>

#define N_NODES 50000
#define MPAD    50048   // round up to 64-row GEMM tiles
#define DEG     16
#define BATCH   1024
#define F_IN    128
#define HID     128
#define F_OUT   64
#define FE_H    8
#define FN_H    128
#define GP_H    128
#define E_TOT   (N_NODES * DEG)
#define NXCD    8
#define GEMM1_BLOCKS (MPAD / 64)            // 782
#define EDGE_BLOCKS  ((E_TOT + 255) / 256)  // 3125

typedef __attribute__((ext_vector_type(8))) short          bf16x8;
typedef __attribute__((ext_vector_type(8))) unsigned short u16x8;
typedef __attribute__((ext_vector_type(4))) float          f32x4;
typedef unsigned long long u64;

__device__ __forceinline__ unsigned short f2bf(float f) {
    unsigned int u = __builtin_bit_cast(unsigned int, f);
    u += 0x7FFFu + ((u >> 16) & 1u);   // round-to-nearest-even
    return (unsigned short)(u >> 16);
}
__device__ __forceinline__ float bf2f(unsigned short s) {
    unsigned int u = ((unsigned int)s) << 16;
    return __builtin_bit_cast(float, u);
}

// ---------------------------------------------------------------------------
// 1. prep: zero 8 histogram copies + feat, convert W1/W2/W3 -> bf16^T
// ---------------------------------------------------------------------------
__global__ void k_prep(u64* __restrict__ packed, float* __restrict__ feat,
                       const float* __restrict__ W1, const float* __restrict__ W2,
                       const float* __restrict__ W3, unsigned short* __restrict__ Wt1,
                       unsigned short* __restrict__ Wt2, unsigned short* __restrict__ Wt3) {
    int idx = blockIdx.x * blockDim.x + threadIdx.x;
    if (idx < NXCD * MPAD) packed[idx] = 0ull;
    if (idx < F_OUT) feat[idx] = 0.0f;
    if (idx < 16384) {
        int k = idx >> 7, c = idx & 127;
        Wt1[c * 128 + k] = f2bf(W1[idx]);
    } else if (idx < 32768) {
        int t = idx - 16384; int k = t >> 7, c = t & 127;
        Wt2[c * 128 + k] = f2bf(W2[t]);
    } else if (idx < 40960) {
        int t = idx - 32768; int k = t >> 6, c = t & 63;
        Wt3[c * 128 + k] = f2bf(W3[t]);
    }
}

// ---------------------------------------------------------------------------
// 2. FUSED: layer-1 GEMM ∥ edge scatter into the issuing XCD's private
//    histogram copy via workgroup-scope L2 atomics (no cross-XCD sharing:
//    copy index = HW_REG_XCC_ID, so coherence stays within one L2).
// ---------------------------------------------------------------------------
__global__ __launch_bounds__(256) void k_gemm1_edge(
    const float* __restrict__ x, const unsigned short* __restrict__ Wt,
    unsigned short* __restrict__ t,
    const int* __restrict__ nbr, const float* __restrict__ A_w,
    const float* __restrict__ fe_w1, const float* __restrict__ fe_b1,
    const float* __restrict__ fe_w2, const float* __restrict__ fe_b2,
    u64* __restrict__ packed) {
    if (blockIdx.x < GEMM1_BLOCKS) {
        int lane = threadIdx.x & 63;
        int wave = threadIdx.x >> 6;
        int row_in = lane & 15;
        int kb = lane >> 4;                      // 0..3
        int r0 = blockIdx.x * 64 + wave * 16;
        int r  = min(r0 + row_in, N_NODES - 1);  // clamp: no OOB read of x
        f32x4 acc[8];
#pragma unroll
        for (int ct = 0; ct < 8; ++ct) acc[ct] = (f32x4){0.f, 0.f, 0.f, 0.f};
#pragma unroll
        for (int ks = 0; ks < 4; ++ks) {
            const float4* xr = (const float4*)(x + r * 128 + ks * 32 + kb * 8);
            float4 p0 = xr[0], p1 = xr[1];
            bf16x8 a;
            a[0] = (short)f2bf(p0.x); a[1] = (short)f2bf(p0.y);
            a[2] = (short)f2bf(p0.z); a[3] = (short)f2bf(p0.w);
            a[4] = (short)f2bf(p1.x); a[5] = (short)f2bf(p1.y);
            a[6] = (short)f2bf(p1.z); a[7] = (short)f2bf(p1.w);
#pragma unroll
            for (int ct = 0; ct < 8; ++ct) {
                bf16x8 b = *(const bf16x8*)(Wt + (ct * 16 + row_in) * 128 + ks * 32 + kb * 8);
                acc[ct] = __builtin_amdgcn_mfma_f32_16x16x32_bf16(a, b, acc[ct], 0, 0, 0);
            }
        }
#pragma unroll
        for (int ct = 0; ct < 8; ++ct)
#pragma unroll
            for (int rr = 0; rr < 4; ++rr)
                t[(r0 + kb * 4 + rr) * 128 + ct * 16 + row_in] = f2bf(acc[ct][rr]);
    } else {
        int e = (blockIdx.x - GEMM1_BLOCKS) * 256 + threadIdx.x;
        if (e >= E_TOT) return;
        int   c = nbr[e];
        float v = A_w[e];
        float acc = fe_b2[0];
#pragma unroll
        for (int j = 0; j < FE_H; ++j) {
            float hj = fmaf(v, fe_w1[j], fe_b1[j]);
            acc = fmaf(fmaxf(hj, 0.0f), fe_w2[j], acc);
        }
        // fixed-point: bias 32, scale 2^19 (32*2^19 = 2^24 exactly)
        int fx = (int)rintf(fmaf(acc, 524288.0f, 16777216.0f));
        unsigned int xcd;
        asm volatile("s_getreg_b32 %0, hwreg(HW_REG_XCC_ID)" : "=s"(xcd));
        u64* cp = packed + (size_t)(xcd & 7) * MPAD;
        __hip_atomic_fetch_add(&cp[c], (1ull << 32) + (u64)(unsigned int)fx,
                               __ATOMIC_RELAXED, __HIP_MEMORY_SCOPE_WORKGROUP);
    }
}

// ---------------------------------------------------------------------------
// 3. reduce 8 copies -> rd = rsqrt(d), idg = 1/d, nsf (exact integer sum)
// ---------------------------------------------------------------------------
__global__ void k_reduce(const u64* __restrict__ packed, float* __restrict__ rd,
                         float* __restrict__ idg, float* __restrict__ nsf) {
    int i = blockIdx.x * blockDim.x + threadIdx.x;
    if (i >= N_NODES) return;
    u64 cnt = 0; long long lo = 0;
#pragma unroll
    for (int x = 0; x < NXCD; ++x) {
        u64 p = packed[(size_t)x * MPAD + i];
        cnt += p >> 32;
        lo  += (long long)(p & 0xFFFFFFFFull);
    }
    long long noBias = lo - ((long long)cnt << 24);
    float d = 1.0f + (float)cnt;
    rd[i]  = rsqrtf(d);
    idg[i] = 1.0f / d;
    nsf[i] = (float)noBias * (1.0f / 524288.0f);
}

// ---------------------------------------------------------------------------
// 4. FUSED agg (relu) + GEMM: h = relu(agg(t)) kept in LDS, tout = h @ Wt^T
//    64 rows per block; agg phase 256 thr = 16 rows x 16 col-groups.
// ---------------------------------------------------------------------------
template <int OUTC>
__global__ __launch_bounds__(256) void k_agg_gemm(
    const unsigned short* __restrict__ t, const int* __restrict__ nbr,
    const float* __restrict__ rd, const float* __restrict__ idg,
    const float* __restrict__ bias, const unsigned short* __restrict__ Wt,
    unsigned short* __restrict__ tout) {
    __shared__ unsigned short ls[64][136];   // +8 pad: 272B row stride
    __shared__ int   s_nb[64][DEG];
    __shared__ float s_w[64][DEG];
    const int tid  = threadIdx.x;
    const int base = blockIdx.x * 64;
    // stage neighbor ids + weights for all 64 rows
    for (int q = tid; q < 64 * DEG; q += 256) {
        int row = q >> 4, k = q & 15;
        int ii = min(base + row, N_NODES - 1);
        int j = nbr[ii * DEG + k];
        s_nb[row][k] = j;
        s_w[row][k]  = rd[ii] * rd[j];
    }
    __syncthreads();
    // agg: thread (g,sub) handles row r*16+g, cols sub*8..sub*8+7
    const int g = tid >> 4, sub = tid & 15;
    const u16x8* t8 = (const u16x8*)t;
    float4 b0 = ((const float4*)bias)[sub * 2];
    float4 b1 = ((const float4*)bias)[sub * 2 + 1];
    float bv[8] = {b0.x, b0.y, b0.z, b0.w, b1.x, b1.y, b1.z, b1.w};
#pragma unroll
    for (int r = 0; r < 4; ++r) {
        int row = r * 16 + g;
        int ii  = min(base + row, N_NODES - 1);
        float si = idg[ii];
        u16x8 tv = t8[ii * 16 + sub];
        float acc[8];
#pragma unroll
        for (int c = 0; c < 8; ++c) acc[c] = fmaf(bf2f((unsigned short)tv[c]), si, bv[c]);
#pragma unroll
        for (int k = 0; k < DEG; ++k) {
            int   j = s_nb[row][k];
            float w = s_w[row][k];
            u16x8 v = t8[j * 16 + sub];
#pragma unroll
            for (int c = 0; c < 8; ++c) acc[c] = fmaf(w, bf2f((unsigned short)v[c]), acc[c]);
        }
        u16x8 o;
#pragma unroll
        for (int c = 0; c < 8; ++c) o[c] = f2bf(fmaxf(acc[c], 0.0f));
        *(u16x8*)(&ls[row][sub * 8]) = o;
    }
    __syncthreads();
    // GEMM from LDS: wave w does rows w*16..w*16+15
    int lane = tid & 63, wave = tid >> 6;
    int row_in = lane & 15, kb = lane >> 4;
    int lrow = wave * 16 + row_in;
    f32x4 acc2[OUTC / 16];
#pragma unroll
    for (int ct = 0; ct < OUTC / 16; ++ct) acc2[ct] = (f32x4){0.f, 0.f, 0.f, 0.f};
#pragma unroll
    for (int ks = 0; ks < 4; ++ks) {
        bf16x8 a = *(const bf16x8*)(&ls[lrow][ks * 32 + kb * 8]);
#pragma unroll
        for (int ct = 0; ct < OUTC / 16; ++ct) {
            bf16x8 b = *(const bf16x8*)(Wt + (ct * 16 + row_in) * 128 + ks * 32 + kb * 8);
            acc2[ct] = __builtin_amdgcn_mfma_f32_16x16x32_bf16(a, b, acc2[ct], 0, 0, 0);
        }
    }
#pragma unroll
    for (int ct = 0; ct < OUTC / 16; ++ct)
#pragma unroll
        for (int rr = 0; rr < 4; ++rr)
            tout[(base + wave * 16 + kb * 4 + rr) * OUTC + ct * 16 + row_in] = f2bf(acc2[ct][rr]);
}

// ---------------------------------------------------------------------------
// 5. final aggregate (64 cols, no relu): h3 = agg(t3)
// ---------------------------------------------------------------------------
__global__ __launch_bounds__(256) void k_agg64(const unsigned short* __restrict__ t,
                                               const int* __restrict__ nbr,
                                               const float* __restrict__ rd,
                                               const float* __restrict__ idg,
                                               const float* __restrict__ bias,
                                               unsigned short* __restrict__ hout) {
    constexpr int TPN = 8;            // threads per node (16B each)
    constexpr int NPB = 32;           // nodes per block
    __shared__ int   s_nb[NPB][DEG];
    __shared__ float s_w[NPB][DEG];
    int g   = threadIdx.x / TPN;
    int sub = threadIdx.x % TPN;
    int i   = blockIdx.x * NPB + g;
    bool ok = (i < N_NODES);
    if (ok) {
        float di = rd[i];
        for (int k = sub; k < DEG; k += TPN) {
            int j = nbr[i * DEG + k];
            s_nb[g][k] = j;
            s_w[g][k]  = di * rd[j];
        }
    }
    __syncthreads();
    if (!ok) return;
    const u16x8* t8 = (const u16x8*)t;
    float si = idg[i];
    float4 b0 = ((const float4*)bias)[sub * 2];
    float4 b1 = ((const float4*)bias)[sub * 2 + 1];
    float bv[8] = {b0.x, b0.y, b0.z, b0.w, b1.x, b1.y, b1.z, b1.w};
    u16x8 tv = t8[i * TPN + sub];
    float acc[8];
#pragma unroll
    for (int c = 0; c < 8; ++c) acc[c] = fmaf(bf2f((unsigned short)tv[c]), si, bv[c]);
#pragma unroll
    for (int k = 0; k < DEG; ++k) {
        int   j = s_nb[g][k];
        float w = s_w[g][k];
        u16x8 v = t8[j * TPN + sub];
#pragma unroll
        for (int c = 0; c < 8; ++c) acc[c] = fmaf(w, bf2f((unsigned short)v[c]), acc[c]);
    }
    u16x8 o;
#pragma unroll
    for (int c = 0; c < 8; ++c) o[c] = f2bf(acc[c]);
    ((u16x8*)hout)[i * TPN + sub] = o;
}

// ---------------------------------------------------------------------------
// 6. out_feat[c] = sum_b h3[e0_b,c] * h3[e1_b,c]   (h3 bf16)
// ---------------------------------------------------------------------------
__global__ void k_feat(const unsigned short* __restrict__ h3,
                       const int* __restrict__ edge, float* __restrict__ feat) {
    int c = threadIdx.x;  // 0..63
    float acc = 0.0f;
    for (int b = blockIdx.x; b < BATCH; b += gridDim.x) {
        int s = edge[b];
        int d = edge[BATCH + b];
        acc = fmaf(bf2f(h3[s * F_OUT + c]), bf2f(h3[d * F_OUT + c]), acc);
    }
    atomicAdd(&feat[c], acc);
}

// ---------------------------------------------------------------------------
// 7. structural path + final blend. One block (128 thr) per batch edge.
// ---------------------------------------------------------------------------
__global__ __launch_bounds__(128) void k_struct(
    const int* __restrict__ edge, const int* __restrict__ nbr,
    const float* __restrict__ A_w, const float* __restrict__ nsf,
    const float* __restrict__ fn_w1, const float* __restrict__ fn_b1,
    const float* __restrict__ fn_w2, const float* __restrict__ fn_b2,
    const float* __restrict__ gp_w1, const float* __restrict__ gp_b1,
    const float* __restrict__ gp_w2, const float* __restrict__ gp_b2,
    const float* __restrict__ alpha, const float* __restrict__ feat,
    float* __restrict__ out) {
    int b   = blockIdx.x;
    int tid = threadIdx.x;
    __shared__ float wv[32];
    __shared__ int   nv[32];
    __shared__ float red[2];
    __shared__ float red2[2];

    // 32 entries (16 src-nbrs, 16 dst-nbrs); 4 threads per entry share FN MLP
    int e = tid >> 2, sub = tid & 3;
    int which = e >> 4, k = e & 15;
    int ref  = edge[which * BATCH + b];
    int node = nbr[ref * DEG + k];
    float v  = nsf[node];
    float part = 0.0f;
#pragma unroll
    for (int jj = 0; jj < FN_H / 4; ++jj) {
        int j = sub * (FN_H / 4) + jj;
        float hj = fmaf(v, fn_w1[j], fn_b1[j]);
        part = fmaf(fmaxf(hj, 0.0f), fn_w2[j], part);
    }
    part += __shfl_xor(part, 1);
    part += __shfl_xor(part, 2);
    if (sub == 0) {
        wv[e] = A_w[ref * DEG + k] * (part + fn_b2[0]);
        nv[e] = node;
    }
    __syncthreads();

    // 256 (i,j) pairs, 2 per thread
    float ps = 0.0f;
    {
        int p2 = tid, i0 = p2 >> 4, j0 = p2 & 15;
        if (nv[i0] == nv[16 + j0]) ps += wv[i0] * wv[16 + j0];
        p2 = tid + 128; i0 = p2 >> 4; j0 = p2 & 15;
        if (nv[i0] == nv[16 + j0]) ps += wv[i0] * wv[16 + j0];
    }
    for (int off = 1; off < 64; off <<= 1) ps += __shfl_xor(ps, off);
    if ((tid & 63) == 0) red[tid >> 6] = ps;
    __syncthreads();
    float os = red[0] + red[1];

    // gp MLP (GP_H = 128 = blockDim)
    float hj = fmaf(os, gp_w1[tid], gp_b1[tid]);
    float g  = fmaxf(hj, 0.0f) * gp_w2[tid];
    for (int off = 1; off < 64; off <<= 1) g += __shfl_xor(g, off);
    if ((tid & 63) == 0) red2[tid >> 6] = g;
    __syncthreads();
    float raw = red2[0] + red2[1] + gp_b2[0];
    float sig = 1.0f / (1.0f + expf(-raw));

    float a0e = alpha[0], a1e = alpha[1];
    float m  = fmaxf(a0e, a1e);
    float e0 = expf(a0e - m), e1 = expf(a1e - m);
    float inv = 1.0f / (e0 + e1);
    float a0 = e0 * inv, a1 = e1 * inv;

    if (tid < F_OUT)
        out[b * F_OUT + tid] = fmaf(a1, feat[tid], a0 * sig) + 1e-15f;
    if (tid == 0) {
        out[BATCH * F_OUT + b] = sig;                          // out_struct_sig
        out[BATCH * F_OUT + BATCH + F_OUT + b] = raw;          // out_struct_raw
    }
    if (b == 0 && tid < F_OUT)
        out[BATCH * F_OUT + BATCH + tid] = feat[tid];          // out_feat
}

// ---------------------------------------------------------------------------
extern "C" void kernel_launch(void* const* d_in, const int* in_sizes, int n_in,
                              void* d_out, int out_size, void* d_ws, size_t ws_size,
                              hipStream_t stream) {
    const int*   edge  = (const int*)d_in[0];
    const float* x     = (const float*)d_in[1];
    const int*   nbr   = (const int*)d_in[2];
    const float* A_w   = (const float*)d_in[3];
    const float* W1    = (const float*)d_in[4];
    const float* b1    = (const float*)d_in[5];
    const float* W2    = (const float*)d_in[6];
    const float* b2    = (const float*)d_in[7];
    const float* W3    = (const float*)d_in[8];
    const float* b3    = (const float*)d_in[9];
    const float* fe_w1 = (const float*)d_in[10];
    const float* fe_b1 = (const float*)d_in[11];
    const float* fe_w2 = (const float*)d_in[12];
    const float* fe_b2 = (const float*)d_in[13];
    const float* fn_w1 = (const float*)d_in[14];
    const float* fn_b1 = (const float*)d_in[15];
    const float* fn_w2 = (const float*)d_in[16];
    const float* fn_b2 = (const float*)d_in[17];
    const float* gp_w1 = (const float*)d_in[18];
    const float* gp_b1 = (const float*)d_in[19];
    const float* gp_w2 = (const float*)d_in[20];
    const float* gp_b2 = (const float*)d_in[21];
    const float* alpha = (const float*)d_in[22];

    char* w = (char*)d_ws;
    u64*   packed = (u64*)w;                         // 8*50048*8 = 3,203,072 B
    float* rd     = (float*)(w + 3203072);           // 200192 B
    float* idg    = rd + MPAD;
    float* nsf    = idg + MPAD;
    float* feat   = nsf + MPAD;                      // 64 floats
    unsigned short* tA  = (unsigned short*)(w + 3803904 + 256);     // MPAD*128 bf16
    unsigned short* tB  = tA + (size_t)MPAD * 128;                  // MPAD*128 bf16
    unsigned short* Wt1 = tB + (size_t)MPAD * 128;                  // 128*128
    unsigned short* Wt2 = Wt1 + 128 * 128;                          // 128*128
    unsigned short* Wt3 = Wt2 + 128 * 128;                          // 64*128
    float* out  = (float*)d_out;

    k_prep<<<(NXCD * MPAD + 255) / 256, 256, 0, stream>>>(packed, feat, W1, W2, W3,
                                                          Wt1, Wt2, Wt3);
    // layer-1 GEMM ∥ edge scatter (per-XCD private histogram, L2 atomics)
    k_gemm1_edge<<<GEMM1_BLOCKS + EDGE_BLOCKS, 256, 0, stream>>>(
        x, Wt1, tA, nbr, A_w, fe_w1, fe_b1, fe_w2, fe_b2, packed);
    k_reduce<<<(N_NODES + 255) / 256, 256, 0, stream>>>(packed, rd, idg, nsf);
    // layer 2 = agg1 (LDS) + gemm2
    k_agg_gemm<128><<<MPAD / 64, 256, 0, stream>>>(tA, nbr, rd, idg, b1, Wt2, tB);
    // layer 3 = agg2 (LDS) + gemm3
    k_agg_gemm<64><<<MPAD / 64, 256, 0, stream>>>(tB, nbr, rd, idg, b2, Wt3, tA);
    // final aggregate (no relu)
    k_agg64<<<(N_NODES + 31) / 32, 256, 0, stream>>>(tA, nbr, rd, idg, b3, tB);

    k_feat<<<256, 64, 0, stream>>>(tB, edge, feat);
    k_struct<<<BATCH, 128, 0, stream>>>(edge, nbr, A_w, nsf,
                                        fn_w1, fn_b1, fn_w2, fn_b2,
                                        gp_w1, gp_b1, gp_w2, gp_b2,
                                        alpha, feat, out);
}